// Round 7
// baseline (44084.702 us; speedup 1.0000x reference)
//
#include <hip/hip_runtime.h>
#include <hip/hip_cooperative_groups.h>

namespace cg = cooperative_groups;

typedef unsigned short u16;
typedef __attribute__((ext_vector_type(8))) short short8;
typedef __attribute__((ext_vector_type(4))) short short4v;
typedef __attribute__((ext_vector_type(4))) float f32x4;

#define NB 256      // batch
#define TE 512      // encoder T
#define DK 256      // key dim
#define DV 256      // value dim
#define HH 512      // hidden
#define NV 35       // vocab
#define STEPS 300
#define TLEN 301
#define K1 1280     // LSTM1 inner dim: emb(512) + ctx(256) + h1(512)
#define K2 768      // LSTM2 inner dim: h1(512) + h2(256)

__device__ __forceinline__ float bf2f(u16 u){ return __uint_as_float(((unsigned)u)<<16); }
__device__ __forceinline__ u16 f2bf(float f){
  unsigned u = __float_as_uint(f);
  u += 0x7fffu + ((u>>16)&1u);   // RNE
  return (u16)(u>>16);
}
__device__ __forceinline__ void splitbf(float f, short& hi, short& lo){
  u16 h = f2bf(f);
  float r = f - bf2f(h);
  hi = (short)h; lo = (short)f2bf(r);
}
__device__ __forceinline__ float sigm(float x){ return 1.f/(1.f+expf(-x)); }

// ---------------- conversion kernel (once per launch) ----------------
__global__ void conv_cat_split(u16* __restrict__ dhi, u16* __restrict__ dlo,
                               const float* __restrict__ s1, const float* __restrict__ s2,
                               int k1, int k2, int total8){
  int i = blockIdx.x*blockDim.x + threadIdx.x;
  if (i >= total8) return;
  int ktot = k1 + k2;
  long e = (long)i*8;
  int r = (int)(e / ktot); int k = (int)(e - (long)r*ktot);
  const float* s = (k < k1) ? (s1 + (size_t)r*k1 + k) : (s2 + (size_t)r*k2 + (k-k1));
  short8 oh, ol;
  #pragma unroll
  for (int q=0;q<8;++q){ short h,l; splitbf(s[q],h,l); oh[q]=h; ol[q]=l; }
  *(short8*)(dhi + e) = oh;
  *(short8*)(dlo + e) = ol;
}

struct Params {
  const float *enc_key, *enc_val;
  const int *text, *lens;
  const float *emb;
  const u16 *W1h, *W1l, *W2h, *W2l;
  const float *bi1, *bh1, *bi2, *bh2;
  const float *Wout, *bout;
  float *h1b, *c1, *h2b, *c2, *ctx, *out;
};

// ============ persistent cooperative kernel: all 300 steps ============
// 256 blocks x 512 threads (8 waves). Per step: phase1 lstm1 GEMM+cell,
// phase2 lstm2 (blocks<128), phase3 per-row attention+out. 3 grid syncs.
__global__ __launch_bounds__(512, 1) void decoder_k(Params P)
{
  cg::grid_group grid = cg::this_grid();
  // GEMM staging (phases 1&2): A split hi/lo, B split hi/lo, double-buffered
  __shared__ __align__(16) u16 AhS[2][2][4][16][8], AlS[2][2][4][16][8];  // [buf][nhalf][kc][row][8]
  __shared__ __align__(16) u16 BhS[2][4][4][16][8], BlS[2][4][4][16][8];  // [buf][gate][kc][j][8]
  __shared__ float gex[4][32][16];   // gate exchange for cell update
  // attention phase
  __shared__ float h2s[DK];
  __shared__ float e_s[TE];
  __shared__ float ctx_s[DV];
  __shared__ float ctxp[8][DV];
  __shared__ float red_s[16];

  const int b = blockIdx.x, tid = threadIdx.x;
  const int w = tid>>6, lane = tid&63;
  const int nh = w&1, gw = w>>1;          // MFMA wave role: (n-half, gate)
  const bool isA = tid < 256;             // waves 0-3 stage A, 4-7 stage B
  const int an = tid>>3, akq = tid&7;     // A: row 0..31, k-quad (k=akq*4)
  const int jl  = (tid-256)>>2;           // B: 0..63 (gate*16+jhl)
  const int koB = ((tid-256)&3)*8;        // B: k-offset 0/8/16/24
  const int gs = (jl>>4)&3, jhl = jl&15;
  const int en = tid>>4, ej = tid&15;     // epilogue role: (n 0..31, jh 0..15)

  const int jh0_1 = ((b&7)*4 + ((b>>3)&3))*16;  // XCD-grouped jh tiles
  const int n0_1  = (b>>5)*32;
  const int jh0_2 = ((b&7)*2 + ((b>>3)&1))*16;
  const int n0_2  = (b>>4)*32;
  const bool p2act = b < 128;

  // biases hoisted out of the time loop
  float b1i = P.bi1[jh0_1+ej]      + P.bh1[jh0_1+ej];
  float b1f = P.bi1[HH+jh0_1+ej]   + P.bh1[HH+jh0_1+ej];
  float b1g = P.bi1[2*HH+jh0_1+ej] + P.bh1[2*HH+jh0_1+ej];
  float b1o = P.bi1[3*HH+jh0_1+ej] + P.bh1[3*HH+jh0_1+ej];
  float b2i=0.f,b2f=0.f,b2g=0.f,b2o=0.f;
  if (p2act){
    b2i = P.bi2[jh0_2+ej]      + P.bh2[jh0_2+ej];
    b2f = P.bi2[DK+jh0_2+ej]   + P.bh2[DK+jh0_2+ej];
    b2g = P.bi2[2*DK+jh0_2+ej] + P.bh2[2*DK+jh0_2+ej];
    b2o = P.bi2[3*DK+jh0_2+ej] + P.bh2[3*DK+jh0_2+ej];
  }
  // weight row pointers (constant over steps)
  const u16* pB1h = P.W1h + (size_t)(gs*512 + jh0_1 + jhl)*K1 + koB;
  const u16* pB1l = P.W1l + (size_t)(gs*512 + jh0_1 + jhl)*K1 + koB;
  const u16* pB2h = P.W2h + (size_t)(gs*256 + jh0_2 + jhl)*K2 + koB;
  const u16* pB2l = P.W2l + (size_t)(gs*256 + jh0_2 + jhl)*K2 + koB;

  for (int t=0; t<STEPS; ++t){
    const int par = t&1;
    const float* h1_old = P.h1b + (size_t)par*NB*HH;
    float*       h1_new = P.h1b + (size_t)(par^1)*NB*HH;
    const float* h2_old = P.h2b + (size_t)par*NB*DK;
    float*       h2_new = P.h2b + (size_t)(par^1)*NB*DK;

    // ===================== phase 1: LSTM1 =====================
    {
      const float* aemb = nullptr; const float* actx = nullptr; const float* ah1 = nullptr;
      if (isA){
        int arow = n0_1 + an;
        aemb = P.emb + (size_t)P.text[arow*TLEN + t]*HH;
        actx = P.ctx + (size_t)arow*DV;
        ah1  = h1_old + (size_t)arow*HH;
      }
      f32x4 acc = {0.f,0.f,0.f,0.f};
      float4 av; short8 rbh, rbl;
      if (isA){
        int k = akq*4;
        const float* src = (k<512)? (aemb+k) : (k<768)? (actx+(k-512)) : (ah1+(k-768));
        av = *(const float4*)src;
      } else {
        rbh = *(const short8*)pB1h;
        rbl = *(const short8*)pB1l;
      }
      int cur = 0;
      for (int k0=0; k0<K1; k0+=32){
        if (isA){
          short4v hv, lv; short h,l;
          splitbf(av.x,h,l); hv[0]=h; lv[0]=l;
          splitbf(av.y,h,l); hv[1]=h; lv[1]=l;
          splitbf(av.z,h,l); hv[2]=h; lv[2]=l;
          splitbf(av.w,h,l); hv[3]=h; lv[3]=l;
          *(short4v*)&AhS[cur][an>>4][akq>>1][an&15][(akq&1)*4] = hv;
          *(short4v*)&AlS[cur][an>>4][akq>>1][an&15][(akq&1)*4] = lv;
          if (k0+32 < K1){
            int k = k0+32+akq*4;
            const float* src = (k<512)? (aemb+k) : (k<768)? (actx+(k-512)) : (ah1+(k-768));
            av = *(const float4*)src;
          }
        } else {
          *(short8*)&BhS[cur][gs][koB>>3][jhl][0] = rbh;
          *(short8*)&BlS[cur][gs][koB>>3][jhl][0] = rbl;
          if (k0+32 < K1){
            rbh = *(const short8*)(pB1h + k0+32);
            rbl = *(const short8*)(pB1l + k0+32);
          }
        }
        __syncthreads();
        short8 afh = *(const short8*)&AhS[cur][nh][lane>>4][lane&15][0];
        short8 afl = *(const short8*)&AlS[cur][nh][lane>>4][lane&15][0];
        short8 bfh = *(const short8*)&BhS[cur][gw][lane>>4][lane&15][0];
        short8 bfl = *(const short8*)&BlS[cur][gw][lane>>4][lane&15][0];
        acc = __builtin_amdgcn_mfma_f32_16x16x32_bf16(afh, bfh, acc, 0,0,0);
        acc = __builtin_amdgcn_mfma_f32_16x16x32_bf16(afl, bfh, acc, 0,0,0);
        acc = __builtin_amdgcn_mfma_f32_16x16x32_bf16(afh, bfl, acc, 0,0,0);
        cur ^= 1;
      }
      #pragma unroll
      for (int r=0;r<4;++r) gex[gw][nh*16 + (lane>>4)*4 + r][lane&15] = acc[r];
      __syncthreads();
      {
        float iv = sigm(gex[0][en][ej] + b1i);
        float fv = sigm(gex[1][en][ej] + b1f);
        float gv = tanhf(gex[2][en][ej] + b1g);
        float ov = sigm(gex[3][en][ej] + b1o);
        size_t idx = (size_t)(n0_1+en)*HH + jh0_1+ej;
        float cn = fv*P.c1[idx] + iv*gv;
        P.c1[idx] = cn;
        h1_new[idx] = ov*tanhf(cn);
      }
    }
    grid.sync();

    // ===================== phase 2: LSTM2 (blocks < 128) =====================
    if (p2act){
      const float* ah1 = nullptr; const float* ah2 = nullptr;
      if (isA){
        ah1 = h1_new + (size_t)(n0_2+an)*HH;
        ah2 = h2_old + (size_t)(n0_2+an)*DK;
      }
      f32x4 acc = {0.f,0.f,0.f,0.f};
      float4 av; short8 rbh, rbl;
      if (isA){
        int k = akq*4;
        const float* src = (k<512)? (ah1+k) : (ah2+(k-512));
        av = *(const float4*)src;
      } else {
        rbh = *(const short8*)pB2h;
        rbl = *(const short8*)pB2l;
      }
      int cur = 0;
      for (int k0=0; k0<K2; k0+=32){
        if (isA){
          short4v hv, lv; short h,l;
          splitbf(av.x,h,l); hv[0]=h; lv[0]=l;
          splitbf(av.y,h,l); hv[1]=h; lv[1]=l;
          splitbf(av.z,h,l); hv[2]=h; lv[2]=l;
          splitbf(av.w,h,l); hv[3]=h; lv[3]=l;
          *(short4v*)&AhS[cur][an>>4][akq>>1][an&15][(akq&1)*4] = hv;
          *(short4v*)&AlS[cur][an>>4][akq>>1][an&15][(akq&1)*4] = lv;
          if (k0+32 < K2){
            int k = k0+32+akq*4;
            const float* src = (k<512)? (ah1+k) : (ah2+(k-512));
            av = *(const float4*)src;
          }
        } else {
          *(short8*)&BhS[cur][gs][koB>>3][jhl][0] = rbh;
          *(short8*)&BlS[cur][gs][koB>>3][jhl][0] = rbl;
          if (k0+32 < K2){
            rbh = *(const short8*)(pB2h + k0+32);
            rbl = *(const short8*)(pB2l + k0+32);
          }
        }
        __syncthreads();
        short8 afh = *(const short8*)&AhS[cur][nh][lane>>4][lane&15][0];
        short8 afl = *(const short8*)&AlS[cur][nh][lane>>4][lane&15][0];
        short8 bfh = *(const short8*)&BhS[cur][gw][lane>>4][lane&15][0];
        short8 bfl = *(const short8*)&BlS[cur][gw][lane>>4][lane&15][0];
        acc = __builtin_amdgcn_mfma_f32_16x16x32_bf16(afh, bfh, acc, 0,0,0);
        acc = __builtin_amdgcn_mfma_f32_16x16x32_bf16(afl, bfh, acc, 0,0,0);
        acc = __builtin_amdgcn_mfma_f32_16x16x32_bf16(afh, bfl, acc, 0,0,0);
        cur ^= 1;
      }
      #pragma unroll
      for (int r=0;r<4;++r) gex[gw][nh*16 + (lane>>4)*4 + r][lane&15] = acc[r];
      __syncthreads();
      {
        float iv = sigm(gex[0][en][ej] + b2i);
        float fv = sigm(gex[1][en][ej] + b2f);
        float gv = tanhf(gex[2][en][ej] + b2g);
        float ov = sigm(gex[3][en][ej] + b2o);
        size_t idx = (size_t)(n0_2+en)*DK + jh0_2+ej;
        float cn = fv*P.c2[idx] + iv*gv;
        P.c2[idx] = cn;
        h2_new[idx] = ov*tanhf(cn);
      }
    }
    grid.sync();

    // ===================== phase 3: attention + output (row n = b) =====================
    {
      const int n = b;
      int L = P.lens[n] >> 3;
      if (tid < DK) h2s[tid] = h2_new[(size_t)n*DK + tid];
      __syncthreads();
      float qreg[32];
      {
        int off = (lane&7)*32;
        #pragma unroll
        for (int q=0;q<32;q+=4){
          float4 v4 = *(const float4*)&h2s[off+q];
          qreg[q]=v4.x; qreg[q+1]=v4.y; qreg[q+2]=v4.z; qreg[q+3]=v4.w;
        }
      }
      const float* kb = P.enc_key + (size_t)n*TE*DK;
      for (int r = w*8 + (lane>>3); r < L; r += 64){
        const float* kr = kb + (size_t)r*DK + (lane&7)*32;
        float s = 0.f;
        #pragma unroll
        for (int q=0;q<32;q+=4){
          float4 kv = *(const float4*)(kr + q);
          s += kv.x*qreg[q] + kv.y*qreg[q+1] + kv.z*qreg[q+2] + kv.w*qreg[q+3];
        }
        s += __shfl_xor(s,1); s += __shfl_xor(s,2); s += __shfl_xor(s,4);
        if ((lane&7)==0) e_s[r] = s;
      }
      __syncthreads();
      float v = (tid < L) ? e_s[tid] : -1e30f;
      float m = v;
      #pragma unroll
      for (int o=1;o<64;o<<=1) m = fmaxf(m, __shfl_xor(m,o));
      if (lane==0) red_s[w] = m;
      __syncthreads();
      m = red_s[0];
      #pragma unroll
      for (int q=1;q<8;++q) m = fmaxf(m, red_s[q]);
      float p = (tid < L) ? expf(v-m) : 0.f;
      float sm = p;
      #pragma unroll
      for (int o=1;o<64;o<<=1) sm += __shfl_xor(sm,o);
      if (lane==0) red_s[8+w] = sm;
      __syncthreads();
      sm = red_s[8];
      #pragma unroll
      for (int q=1;q<8;++q) sm += red_s[8+q];
      e_s[tid] = p * (1.f/sm);
      __syncthreads();
      float4 cacc = {0.f,0.f,0.f,0.f};
      const float* vpb = P.enc_val + (size_t)n*TE*DV + lane*4;
      for (int r = w; r < L; r += 8){
        float a = e_s[r];
        float4 vv4 = *(const float4*)(vpb + (size_t)r*DV);
        cacc.x += a*vv4.x; cacc.y += a*vv4.y; cacc.z += a*vv4.z; cacc.w += a*vv4.w;
      }
      *(float4*)&ctxp[w][lane*4] = cacc;
      __syncthreads();
      if (tid < DV){
        float cv = 0.f;
        #pragma unroll
        for (int q=0;q<8;++q) cv += ctxp[q][tid];
        ctx_s[tid] = cv;
        P.ctx[(size_t)n*DV + tid] = cv;
      }
      __syncthreads();
      #pragma unroll
      for (int vb2=0; vb2<2; ++vb2){
        int vvv = vb2*32 + (tid>>4);
        if (vvv < NV){
          int kbase = (tid&15)*32;
          float s = 0.f;
          #pragma unroll
          for (int q=0;q<32;q+=4){
            float4 w4 = *(const float4*)(P.Wout + (size_t)vvv*512 + kbase + q);
            int k = kbase + q;
            const float* xs = (k < DK)? &h2s[k] : &ctx_s[k-DK];
            s += w4.x*xs[0] + w4.y*xs[1] + w4.z*xs[2] + w4.w*xs[3];
          }
          s += __shfl_xor(s,1); s += __shfl_xor(s,2); s += __shfl_xor(s,4); s += __shfl_xor(s,8);
          if ((tid&15)==0) P.out[((size_t)n*STEPS + t)*NV + vvv] = s + P.bout[vvv];
        }
      }
    }
    grid.sync();
  }
}

// ---------------- host ----------------
extern "C" void kernel_launch(void* const* d_in, const int* in_sizes, int n_in,
                              void* d_out, int out_size, void* d_ws, size_t ws_size,
                              hipStream_t stream)
{
  const float* enc_key = (const float*)d_in[0];
  const float* enc_val = (const float*)d_in[1];
  const int*   text    = (const int*)d_in[2];
  const int*   lens    = (const int*)d_in[3];
  const float* emb     = (const float*)d_in[5];
  const float* W_ih1   = (const float*)d_in[6];
  const float* W_hh1   = (const float*)d_in[7];
  const float* b_ih1   = (const float*)d_in[8];
  const float* b_hh1   = (const float*)d_in[9];
  const float* W_ih2   = (const float*)d_in[10];
  const float* W_hh2   = (const float*)d_in[11];
  const float* b_ih2   = (const float*)d_in[12];
  const float* b_hh2   = (const float*)d_in[13];
  const float* W_out   = (const float*)d_in[14];
  const float* b_out   = (const float*)d_in[15];
  float* out = (float*)d_out;

  char* ws = (char*)d_ws;
  size_t off = 0;
  auto alloc = [&](size_t bytes)->char*{
    char* p = ws + off; off = (off + bytes + 255) & ~(size_t)255; return p;
  };

  u16* Wc1h = (u16*)alloc((size_t)2048*K1*2);
  u16* Wc1l = (u16*)alloc((size_t)2048*K1*2);
  u16* Wc2h = (u16*)alloc((size_t)1024*K2*2);
  u16* Wc2l = (u16*)alloc((size_t)1024*K2*2);
  float* h1b = (float*)alloc((size_t)2*NB*HH*4);
  float* h2b = (float*)alloc((size_t)2*NB*DK*4);
  float* ctx = (float*)alloc((size_t)NB*DV*4);
  float* c1  = (float*)alloc((size_t)NB*HH*4);
  float* c2  = (float*)alloc((size_t)NB*DK*4);

  // zero recurrent state (contiguous block h1b..c2)
  size_t zbytes = (char*)c2 + (size_t)NB*DK*4 - (char*)h1b;
  (void)hipMemsetAsync(h1b, 0, zbytes, stream);

  {
    int t8 = 2048*K1/8;
    conv_cat_split<<<(t8+255)/256, 256, 0, stream>>>(Wc1h, Wc1l, W_ih1, W_hh1, 768, 512, t8);
  }
  {
    int t8 = 1024*K2/8;
    conv_cat_split<<<(t8+255)/256, 256, 0, stream>>>(Wc2h, Wc2l, W_ih2, W_hh2, 512, 256, t8);
  }

  Params p;
  p.enc_key = enc_key; p.enc_val = enc_val; p.text = text; p.lens = lens;
  p.emb = emb;
  p.W1h = Wc1h; p.W1l = Wc1l; p.W2h = Wc2h; p.W2l = Wc2l;
  p.bi1 = b_ih1; p.bh1 = b_hh1; p.bi2 = b_ih2; p.bh2 = b_hh2;
  p.Wout = W_out; p.bout = b_out;
  p.h1b = h1b; p.c1 = c1; p.h2b = h2b; p.c2 = c2; p.ctx = ctx; p.out = out;

  void* kargs[] = { &p };
  (void)hipLaunchCooperativeKernel((void*)decoder_k, dim3(256), dim3(512), kargs, 0, stream);
}